// Round 12
// baseline (1483.958 us; speedup 1.0000x reference)
//
#include <hip/hip_runtime.h>
#include <hip/hip_bf16.h>
#include <math.h>

#define H 768
#define NH 12
#define DH 64
#define NL 6
#define FF 3072
#define LL 4096
#define GG 64
#define NCMAX 32

#define MATSZ (H * H)
#define OFF_QG ((size_t)5 * MATSZ)
#define OFF_O  ((size_t)6 * MATSZ)
#define OFF_W1 ((size_t)7 * MATSZ)
#define OFF_W2 (OFF_W1 + (size_t)H * FF)
#define WT_ELEMS (OFF_W2 + (size_t)FF * H)

typedef unsigned short u16;
typedef __attribute__((ext_vector_type(8))) unsigned short us8;
typedef __attribute__((ext_vector_type(4))) unsigned short us4;
typedef __attribute__((ext_vector_type(8))) __bf16 bf16x8;
typedef __attribute__((ext_vector_type(4))) float f32x4;

__device__ __forceinline__ float bf2f(u16 u) {
  unsigned v = ((unsigned)u) << 16;
  return __builtin_bit_cast(float, v);
}
__device__ __forceinline__ u16 f2bf(float f) {
  unsigned u = __builtin_bit_cast(unsigned, f);
  unsigned r = (u + 0x7fffu + ((u >> 16) & 1u)) >> 16;
  return (u16)r;
}
__device__ __forceinline__ float geluf(float a) {
  return 0.5f * a * (1.f + erff(a * 0.70710678118654752440f));
}
__device__ __forceinline__ float wredsum(float v) {
  #pragma unroll
  for (int o = 32; o; o >>= 1) v += __shfl_xor(v, o);
  return v;
}
__device__ __forceinline__ float wredmax(float v) {
  #pragma unroll
  for (int o = 32; o; o >>= 1) v = fmaxf(v, __shfl_xor(v, o));
  return v;
}
__device__ __forceinline__ void gld16(const u16* g, u16* l) {
  __builtin_amdgcn_global_load_lds(
      (const __attribute__((address_space(1))) unsigned int*)(const void*)g,
      (__attribute__((address_space(3))) unsigned int*)(void*)l, 16, 0, 0);
}
__device__ __forceinline__ void tswz(int& bx, int& by) {
  int nx = gridDim.x, ny = gridDim.y;
  int flat = blockIdx.y * nx + blockIdx.x;
  int nwg = nx * ny;
  if ((nwg & 7) == 0) {
    int c = nwg >> 3;
    flat = (flat & 7) * c + (flat >> 3);
  }
  bx = flat % nx;
  by = flat / nx;
}

// ---------------- embed + LN (writes xgb rows for global positions) ----------------
__global__ __launch_bounds__(256) void embed_ln_k(
    const float* __restrict__ et, const float* __restrict__ ep, const int* __restrict__ ids,
    const float* __restrict__ sc, const float* __restrict__ bi,
    const int* __restrict__ ginv,
    float* __restrict__ x, u16* __restrict__ xb, u16* __restrict__ xgb)
{
  int r = blockIdx.x, t = threadIdx.x;
  int tok = ids[r];
  if (tok < 0) tok = 0;
  if (tok >= 50272) tok = 50271;
  int gi = ginv[r];
  __shared__ float red[4];
  float v[3];
  #pragma unroll
  for (int e = 0; e < 3; ++e) {
    int c = t + e * 256;
    v[e] = et[(size_t)tok * H + c] + ep[(size_t)r * H + c];
  }
  float s = v[0] + v[1] + v[2];
  s = wredsum(s);
  if ((t & 63) == 0) red[t >> 6] = s;
  __syncthreads();
  float mean = (red[0] + red[1] + red[2] + red[3]) * (1.f / 768.f);
  __syncthreads();
  float q = 0.f;
  #pragma unroll
  for (int e = 0; e < 3; ++e) { float d = v[e] - mean; q += d * d; }
  q = wredsum(q);
  if ((t & 63) == 0) red[t >> 6] = q;
  __syncthreads();
  float var = (red[0] + red[1] + red[2] + red[3]) * (1.f / 768.f);
  float rs = rsqrtf(var + 1e-5f);
  #pragma unroll
  for (int e = 0; e < 3; ++e) {
    int c = t + e * 256;
    float o = (v[e] - mean) * rs * sc[c] + bi[c];
    x[(size_t)r * H + c] = o;
    u16 ob16 = f2bf(o);
    xb[(size_t)r * H + c] = ob16;
    if (gi >= 0) xgb[(size_t)gi * H + c] = ob16;
  }
}

// ---------------- LN over x + bias + sum of Z partial buffers ----------------
template<int Z>
__global__ __launch_bounds__(256) void ln_res2_k(
    float* __restrict__ x, const float* __restrict__ part, const float* __restrict__ bias,
    const float* __restrict__ sc, const float* __restrict__ bi,
    const int* __restrict__ ginv, u16* __restrict__ xb, u16* __restrict__ xgb)
{
  int r = blockIdx.x, t = threadIdx.x;
  int gi = ginv[r];
  __shared__ float red[4];
  float v[3];
  #pragma unroll
  for (int e = 0; e < 3; ++e) {
    int c = t + e * 256;
    float a = x[(size_t)r * H + c] + bias[c];
    #pragma unroll
    for (int z = 0; z < Z; ++z)
      a += part[(size_t)z * LL * H + (size_t)r * H + c];
    v[e] = a;
  }
  float s = v[0] + v[1] + v[2];
  s = wredsum(s);
  if ((t & 63) == 0) red[t >> 6] = s;
  __syncthreads();
  float mean = (red[0] + red[1] + red[2] + red[3]) * (1.f / 768.f);
  __syncthreads();
  float q = 0.f;
  #pragma unroll
  for (int e = 0; e < 3; ++e) { float d = v[e] - mean; q += d * d; }
  q = wredsum(q);
  if ((t & 63) == 0) red[t >> 6] = q;
  __syncthreads();
  float var = (red[0] + red[1] + red[2] + red[3]) * (1.f / 768.f);
  float rs = rsqrtf(var + 1e-5f);
  #pragma unroll
  for (int e = 0; e < 3; ++e) {
    int c = t + e * 256;
    float o = (v[e] - mean) * rs * sc[c] + bi[c];
    x[(size_t)r * H + c] = o;
    u16 ob16 = f2bf(o);
    xb[(size_t)r * H + c] = ob16;
    if (gi >= 0) xgb[(size_t)gi * H + c] = ob16;
  }
}

// ---------------- all-layers weight convert+transpose (f32x4 loads, 66-stride LDS) ----------------
__global__ __launch_bounds__(256) void conv_all_k(
    const float* __restrict__ Wq, const float* __restrict__ Wk, const float* __restrict__ Wv,
    const float* __restrict__ Wkg, const float* __restrict__ Wvg, const float* __restrict__ Wqg,
    const float* __restrict__ Wo, const float* __restrict__ W1, const float* __restrict__ W2,
    u16* __restrict__ wt)
{
  int l = blockIdx.y;
  int bid = blockIdx.x, t = threadIdx.x;
  size_t lo = (size_t)l * MATSZ;
  size_t lf = (size_t)l * H * FF;
  u16* wto = wt + (size_t)l * WT_ELEMS;
  const float* src;
  size_t ooff;
  int K, N, tile;
  if (bid < 1008) {
    int m = bid / 144;
    tile = bid % 144;
    K = H; N = H;
    ooff = (size_t)m * MATSZ;
    src = (m == 0 ? Wq : m == 1 ? Wk : m == 2 ? Wv : m == 3 ? Wkg : m == 4 ? Wvg : m == 5 ? Wqg : Wo) + lo;
  } else if (bid < 1584) {
    tile = bid - 1008;
    K = H; N = FF;
    ooff = OFF_W1;
    src = W1 + lf;
  } else {
    tile = bid - 1584;
    K = FF; N = H;
    ooff = OFF_W2;
    src = W2 + lf;
  }
  int KT = K / 64;
  int kt = tile % KT, nt = tile / KT;
  __shared__ u16 sT[64 * 66];   // 132B stride -> 33 banks -> 2-way (free)
  // stage: f32x4 loads (16B/lane), transpose into LDS
  #pragma unroll
  for (int it = 0; it < 4; ++it) {
    int idx = t + it * 256;
    int kk = idx >> 4, q = idx & 15;
    f32x4 val = *reinterpret_cast<const f32x4*>(
        &src[(size_t)(kt * 64 + kk) * N + nt * 64 + q * 4]);
    #pragma unroll
    for (int u = 0; u < 4; ++u)
      sT[(q * 4 + u) * 66 + kk] = f2bf(val[u]);
  }
  __syncthreads();
  #pragma unroll
  for (int it = 0; it < 2; ++it) {
    int idx = t + it * 256;
    int n = idx >> 3, k8 = idx & 7;
    const u16* base = &sT[n * 66 + k8 * 8];
    us8 val;
    unsigned* vp = reinterpret_cast<unsigned*>(&val);
    #pragma unroll
    for (int j = 0; j < 4; ++j)
      vp[j] = *reinterpret_cast<const unsigned*>(base + j * 2);
    *reinterpret_cast<us8*>(&wto[ooff + (size_t)(nt * 64 + n) * K + kt * 64 + k8 * 8]) = val;
  }
}

// ---- GEMM K-loop core (async global_load_lds staging) ----
__device__ __forceinline__ void gemm_loop(
    const u16* __restrict__ A, const u16* __restrict__ Bt,
    int K, int m0, int n0, int kb, int ke,
    u16* lsA, u16* lsB, f32x4 acc[4][4])
{
  int t = threadIdx.x;
  int w = t >> 6, lane = t & 63;
  int cl = lane & 15, kgr = lane >> 4;
  int wm = (w >> 1) * 64, wn = (w & 1) * 64;
  for (int k0 = kb; k0 < ke; k0 += 64) {
    int ml = lane >> 3, k8 = lane & 7;
    #pragma unroll
    for (int it = 0; it < 4; ++it) {
      int chunk = it * 4 + w;
      int m = chunk * 8 + ml;
      gld16(A + (size_t)(m0 + m) * K + k0 + ((k8 ^ (m & 7)) * 8),
            &lsA[chunk * 512 + lane * 8]);
    }
    #pragma unroll
    for (int it = 0; it < 4; ++it) {
      int chunk = it * 4 + w;
      int n = chunk * 8 + ml;
      gld16(Bt + (size_t)(n0 + n) * K + k0 + ((k8 ^ (n & 7)) * 8),
            &lsB[chunk * 512 + lane * 8]);
    }
    __syncthreads();
    #pragma unroll
    for (int kk = 0; kk < 2; ++kk) {
      bf16x8 fa[4], fb[4];
      int k8r = kk * 4 + kgr;
      #pragma unroll
      for (int i = 0; i < 4; ++i) {
        int mr = wm + i * 16 + cl;
        fa[i] = __builtin_bit_cast(bf16x8,
            *reinterpret_cast<const us8*>(&lsA[mr * 64 + ((k8r ^ (mr & 7)) * 8)]));
        int nr = wn + i * 16 + cl;
        fb[i] = __builtin_bit_cast(bf16x8,
            *reinterpret_cast<const us8*>(&lsB[nr * 64 + ((k8r ^ (nr & 7)) * 8)]));
      }
      #pragma unroll
      for (int i = 0; i < 4; ++i)
        #pragma unroll
        for (int j = 0; j < 4; ++j)
          acc[i][j] = __builtin_amdgcn_mfma_f32_16x16x32_bf16(fa[i], fb[j], acc[i][j], 0, 0, 0);
    }
    __syncthreads();
  }
}

template<int ACT>
__global__ __launch_bounds__(256) void gemm_bias_k(
    const u16* __restrict__ A, const u16* __restrict__ Bt, const float* __restrict__ bias,
    u16* __restrict__ outB, int M, int N, int K)
{
  __shared__ u16 lsA[128 * 64];
  __shared__ u16 lsB[128 * 64];
  int bx, by;
  tswz(bx, by);
  int m0 = by * 128, n0 = bx * 128;
  f32x4 zero4 = {0.f, 0.f, 0.f, 0.f};
  f32x4 acc[4][4];
  #pragma unroll
  for (int i = 0; i < 4; ++i)
    #pragma unroll
    for (int j = 0; j < 4; ++j) acc[i][j] = zero4;
  gemm_loop(A, Bt, K, m0, n0, 0, K, lsA, lsB, acc);
  int lane = threadIdx.x & 63, w = threadIdx.x >> 6;
  int cl = lane & 15, kgr = lane >> 4;
  int wm = (w >> 1) * 64, wn = (w & 1) * 64;
  #pragma unroll
  for (int j = 0; j < 4; ++j) {
    int n = n0 + wn + j * 16 + cl;
    float bv = bias[n];
    #pragma unroll
    for (int i = 0; i < 4; ++i) {
      #pragma unroll
      for (int r = 0; r < 4; ++r) {
        int m = m0 + wm + i * 16 + kgr * 4 + r;
        if (m < M) {
          float vv = acc[i][j][r] + bv;
          if (ACT == 1) vv = geluf(vv);
          outB[(size_t)m * N + n] = f2bf(vv);
        }
      }
    }
  }
}

__global__ __launch_bounds__(256) void gemm_part_k(
    const u16* __restrict__ A, const u16* __restrict__ Bt, float* __restrict__ part,
    int M, int N, int K)
{
  __shared__ u16 lsA[128 * 64];
  __shared__ u16 lsB[128 * 64];
  int bx, by;
  tswz(bx, by);
  int m0 = by * 128, n0 = bx * 128;
  int z = blockIdx.z, ns = gridDim.z;
  int ks = K / ns;
  f32x4 zero4 = {0.f, 0.f, 0.f, 0.f};
  f32x4 acc[4][4];
  #pragma unroll
  for (int i = 0; i < 4; ++i)
    #pragma unroll
    for (int j = 0; j < 4; ++j) acc[i][j] = zero4;
  gemm_loop(A, Bt, K, m0, n0, z * ks, (z + 1) * ks, lsA, lsB, acc);
  int lane = threadIdx.x & 63, w = threadIdx.x >> 6;
  int cl = lane & 15, kgr = lane >> 4;
  int wm = (w >> 1) * 64, wn = (w & 1) * 64;
  float* po = part + (size_t)z * LL * H;
  #pragma unroll
  for (int j = 0; j < 4; ++j) {
    int n = n0 + wn + j * 16 + cl;
    #pragma unroll
    for (int i = 0; i < 4; ++i) {
      #pragma unroll
      for (int r = 0; r < 4; ++r) {
        int m = m0 + wm + i * 16 + kgr * 4 + r;
        po[(size_t)m * N + n] = acc[i][j][r];
      }
    }
  }
}

// fused 6-way projection GEMM: z<5 -> (q,k,v,kg,vg) from xb; z==5 -> qg from xgb
__global__ __launch_bounds__(256) void gemm_qkv_k(
    const u16* __restrict__ A, const u16* __restrict__ Ag, const u16* __restrict__ wt,
    const float* c0, const float* c1, const float* c2, const float* c3, const float* c4,
    const float* c5,
    u16* o0, u16* o1, u16* o2, u16* o3, u16* o4, u16* o5)
{
  __shared__ u16 lsA[128 * 64];
  __shared__ u16 lsB[128 * 64];
  int z = blockIdx.z;
  int bx, by;
  tswz(bx, by);
  if (z == 5 && by != 0) return;
  const u16* Bt = wt + (size_t)z * MATSZ;
  const float* bias = z == 0 ? c0 : z == 1 ? c1 : z == 2 ? c2 : z == 3 ? c3 : z == 4 ? c4 : c5;
  u16* outB = z == 0 ? o0 : z == 1 ? o1 : z == 2 ? o2 : z == 3 ? o3 : z == 4 ? o4 : o5;
  const u16* Ap = (z == 5) ? Ag : A;
  int M = (z == 5) ? GG : LL;
  int m0 = by * 128, n0 = bx * 128;
  f32x4 zero4 = {0.f, 0.f, 0.f, 0.f};
  f32x4 acc[4][4];
  #pragma unroll
  for (int i = 0; i < 4; ++i)
    #pragma unroll
    for (int j = 0; j < 4; ++j) acc[i][j] = zero4;
  gemm_loop(Ap, Bt, H, m0, n0, 0, H, lsA, lsB, acc);
  int lane = threadIdx.x & 63, w = threadIdx.x >> 6;
  int cl = lane & 15, kgr = lane >> 4;
  int wm = (w >> 1) * 64, wn = (w & 1) * 64;
  #pragma unroll
  for (int j = 0; j < 4; ++j) {
    int n = n0 + wn + j * 16 + cl;
    float bv = bias[n];
    #pragma unroll
    for (int i = 0; i < 4; ++i) {
      #pragma unroll
      for (int r = 0; r < 4; ++r) {
        int m = m0 + wm + i * 16 + kgr * 4 + r;
        if (m < M) outB[(size_t)m * H + n] = f2bf(acc[i][j][r] + bv);
      }
    }
  }
}

// ---------------- MFMA flash local attention ----------------
__global__ __launch_bounds__(256) void attn_local_k(
    const u16* __restrict__ q, const u16* __restrict__ k, const u16* __restrict__ v,
    const u16* __restrict__ kgp, const u16* __restrict__ vgp,
    const int* __restrict__ gpos, const unsigned char* __restrict__ isg,
    u16* __restrict__ out)
{
  int h = blockIdx.x;
  int q0 = blockIdx.y * 64;
  int nb = q0 >> 8;
  int cs = (nb - 1) * 256;
  int cstart = (q0 >> 6) & 3;
  int t = threadIdx.x;
  int w = t >> 6, lane = t & 63;
  int cl = lane & 15, g = lane >> 4;
  __shared__ u16 sK[64 * 64];
  __shared__ u16 sVt[64 * 64];
  __shared__ u16 sP[64 * 64];
  __shared__ unsigned char sOk[64];
  us8 z8 = {0, 0, 0, 0, 0, 0, 0, 0};
  f32x4 zero4 = {0.f, 0.f, 0.f, 0.f};

  int qrow = q0 + w * 16 + cl;
  bf16x8 qa[2];
  #pragma unroll
  for (int ks = 0; ks < 2; ++ks)
    qa[ks] = __builtin_bit_cast(bf16x8, *reinterpret_cast<const us8*>(
        &q[(size_t)qrow * H + h * 64 + ks * 32 + g * 8]));

  f32x4 O[4];
  #pragma unroll
  for (int dt = 0; dt < 4; ++dt) O[dt] = zero4;
  float mrow[4], lrow[4];
  #pragma unroll
  for (int r = 0; r < 4; ++r) { mrow[r] = -1e30f; lrow[r] = 0.f; }

  for (int ci = 0; ci < 10; ++ci) {
    bool isLocal = (ci < 9);
    int kbase = cs + (cstart + ci) * 64;
    #pragma unroll
    for (int it = 0; it < 2; ++it) {
      int idx = it * 256 + t;
      int key = idx >> 3, d8 = idx & 7;
      int pos;
      if (isLocal) {
        pos = kbase + key;
        pos = pos < 0 ? 0 : (pos >= LL ? LL - 1 : pos);
      } else {
        pos = gpos[key];
        pos = pos < 0 ? 0 : (pos >= LL ? LL - 1 : pos);
      }
      const u16* src = (isLocal ? k : kgp) + (size_t)pos * H + h * 64 + ((d8 ^ (key & 7)) * 8);
      gld16(src, &sK[idx * 8]);
    }
    #pragma unroll
    for (int it = 0; it < 2; ++it) {
      int idx = t + it * 256;
      int key = idx >> 3, d8 = idx & 7;
      us8 val = z8;
      if (isLocal) {
        int pos = kbase + key;
        if (pos >= 0 && pos < LL)
          val = *reinterpret_cast<const us8*>(&v[(size_t)pos * H + h * 64 + d8 * 8]);
      } else {
        int pos = gpos[key];
        if (pos < 0) pos = 0;
        if (pos >= LL) pos = LL - 1;
        val = *reinterpret_cast<const us8*>(&vgp[(size_t)pos * H + h * 64 + d8 * 8]);
      }
      int k8 = key >> 3, klow = key & 7;
      int kswz = (k8 ^ d8) * 8 + klow;
      #pragma unroll
      for (int u = 0; u < 8; ++u)
        sVt[(d8 * 8 + u) * 64 + kswz] = val[u];
    }
    if (t < 64) {
      int ok = 1;
      if (isLocal) {
        int pos = kbase + t;
        ok = (pos >= 0 && pos < LL) ? (isg[pos] ? 0 : 1) : 0;
      }
      sOk[t] = (unsigned char)ok;
    }
    __syncthreads();

    f32x4 S[4];
    #pragma unroll
    for (int T = 0; T < 4; ++T) {
      S[T] = zero4;
      int key = T * 16 + cl;
      #pragma unroll
      for (int ks = 0; ks < 2; ++ks) {
        bf16x8 kf = __builtin_bit_cast(bf16x8, *reinterpret_cast<const us8*>(
            &sK[key * 64 + (((ks * 4 + g) ^ (key & 7)) * 8)]));
        S[T] = __builtin_amdgcn_mfma_f32_16x16x32_bf16(qa[ks], kf, S[T], 0, 0, 0);
      }
    }
    #pragma unroll
    for (int T = 0; T < 4; ++T) {
      int key = T * 16 + cl;
      int okk = sOk[key];
      int pos = kbase + key;
      #pragma unroll
      for (int r = 0; r < 4; ++r) {
        int qp = q0 + w * 16 + g * 4 + r;
        int d = pos - qp;
        bool ok = okk && (!isLocal || (d >= -256 && d <= 256));
        S[T][r] = ok ? S[T][r] * 0.125f : -1e9f;
      }
    }
    float cm[4];
    #pragma unroll
    for (int r = 0; r < 4; ++r) {
      cm[r] = fmaxf(fmaxf(S[0][r], S[1][r]), fmaxf(S[2][r], S[3][r]));
      cm[r] = fmaxf(cm[r], __shfl_xor(cm[r], 1));
      cm[r] = fmaxf(cm[r], __shfl_xor(cm[r], 2));
      cm[r] = fmaxf(cm[r], __shfl_xor(cm[r], 4));
      cm[r] = fmaxf(cm[r], __shfl_xor(cm[r], 8));
    }
    float sc[4];
    #pragma unroll
    for (int r = 0; r < 4; ++r) {
      float mn = fmaxf(mrow[r], cm[r]);
      sc[r] = __expf(mrow[r] - mn);
      mrow[r] = mn;
    }
    float rs[4] = {0.f, 0.f, 0.f, 0.f};
    #pragma unroll
    for (int T = 0; T < 4; ++T) {
      int key = T * 16 + cl;
      #pragma unroll
      for (int r = 0; r < 4; ++r) {
        float sv = S[T][r];
        float pv = sv > -1e8f ? __expf(sv - mrow[r]) : 0.f;
        rs[r] += pv;
        int qloc = w * 16 + g * 4 + r;
        int k8s = (key >> 3) ^ (qloc & 7);
        sP[qloc * 64 + k8s * 8 + (key & 7)] = f2bf(pv);
      }
    }
    #pragma unroll
    for (int r = 0; r < 4; ++r) {
      rs[r] += __shfl_xor(rs[r], 1);
      rs[r] += __shfl_xor(rs[r], 2);
      rs[r] += __shfl_xor(rs[r], 4);
      rs[r] += __shfl_xor(rs[r], 8);
      lrow[r] = lrow[r] * sc[r] + rs[r];
    }
    #pragma unroll
    for (int dt = 0; dt < 4; ++dt)
      #pragma unroll
      for (int r = 0; r < 4; ++r) O[dt][r] *= sc[r];
    int prow = w * 16 + cl;
    #pragma unroll
    for (int ks = 0; ks < 2; ++ks) {
      bf16x8 pf = __builtin_bit_cast(bf16x8, *reinterpret_cast<const us8*>(
          &sP[prow * 64 + (((ks * 4 + g) ^ (prow & 7)) * 8)]));
      #pragma unroll
      for (int dt = 0; dt < 4; ++dt) {
        int dim = dt * 16 + cl;
        int k8s = (ks * 4 + g) ^ ((dim >> 3) & 7);
        bf16x8 vf = __builtin_bit_cast(bf16x8, *reinterpret_cast<const us8*>(
            &sVt[dim * 64 + k8s * 8]));
        O[dt] = __builtin_amdgcn_mfma_f32_16x16x32_bf16(pf, vf, O[dt], 0, 0, 0);
      }
    }
    __syncthreads();
  }
  #pragma unroll
  for (int r = 0; r < 4; ++r) {
    float inv = 1.f / lrow[r];
    int qp = q0 + w * 16 + g * 4 + r;
    #pragma unroll
    for (int dt = 0; dt < 4; ++dt)
      out[(size_t)qp * H + h * 64 + dt * 16 + cl] = f2bf(O[dt][r] * inv);
  }
}

// ---------------- global attention (wide 4-kernel pipeline) ----------------
__global__ __launch_bounds__(256) void ag_score_k(
    const u16* __restrict__ qg, const u16* __restrict__ kg, float* __restrict__ sbuf)
{
  int h = blockIdx.x;
  int kc0 = blockIdx.y * 128;
  int t = threadIdx.x;
  int w = t >> 6, lane = t & 63;
  int cl = lane & 15, g = lane >> 4;
  __shared__ u16 sK[128 * 64];
  #pragma unroll
  for (int it = 0; it < 4; ++it) {
    int idx = it * 256 + t;
    int key = idx >> 3, d8 = idx & 7;
    gld16(kg + (size_t)(kc0 + key) * H + h * 64 + ((d8 ^ (key & 7)) * 8), &sK[idx * 8]);
  }
  int qrow = w * 16 + cl;
  bf16x8 qa[2];
  #pragma unroll
  for (int ks = 0; ks < 2; ++ks)
    qa[ks] = __builtin_bit_cast(bf16x8, *reinterpret_cast<const us8*>(
        &qg[(size_t)qrow * H + h * 64 + ks * 32 + g * 8]));
  __syncthreads();
  f32x4 zero4 = {0.f, 0.f, 0.f, 0.f};
  #pragma unroll
  for (int j = 0; j < 8; ++j) {
    f32x4 S = zero4;
    int key = j * 16 + cl;
    #pragma unroll
    for (int ks = 0; ks < 2; ++ks) {
      bf16x8 kf = __builtin_bit_cast(bf16x8, *reinterpret_cast<const us8*>(
          &sK[key * 64 + (((ks * 4 + g) ^ (key & 7)) * 8)]));
      S = __builtin_amdgcn_mfma_f32_16x16x32_bf16(qa[ks], kf, S, 0, 0, 0);
    }
    #pragma unroll
    for (int r = 0; r < 4; ++r) {
      int grow = w * 16 + g * 4 + r;
      sbuf[((size_t)(h * 64 + grow)) * 4096 + kc0 + key] = S[r] * 0.125f;
    }
  }
}

__global__ __launch_bounds__(256) void ag_soft_k(float* __restrict__ sbuf)
{
  int row = blockIdx.x, t = threadIdx.x;
  float* base = sbuf + (size_t)row * 4096;
  u16* pb = (u16*)(sbuf) + (size_t)row * 8192;
  __shared__ float red[4];
  f32x4 rv[4];
  #pragma unroll
  for (int it = 0; it < 4; ++it)
    rv[it] = *reinterpret_cast<const f32x4*>(base + it * 1024 + t * 4);
  float m = -1e30f;
  #pragma unroll
  for (int it = 0; it < 4; ++it)
    #pragma unroll
    for (int u = 0; u < 4; ++u) m = fmaxf(m, rv[it][u]);
  m = wredmax(m);
  if ((t & 63) == 0) red[t >> 6] = m;
  __syncthreads();
  m = fmaxf(fmaxf(red[0], red[1]), fmaxf(red[2], red[3]));
  __syncthreads();
  float s = 0.f;
  #pragma unroll
  for (int it = 0; it < 4; ++it)
    #pragma unroll
    for (int u = 0; u < 4; ++u) {
      float e = __expf(rv[it][u] - m);
      rv[it][u] = e;
      s += e;
    }
  s = wredsum(s);
  if ((t & 63) == 0) red[t >> 6] = s;
  __syncthreads();
  float inv = 1.f / (red[0] + red[1] + red[2] + red[3]);
  #pragma unroll
  for (int it = 0; it < 4; ++it) {
    us4 o;
    #pragma unroll
    for (int u = 0; u < 4; ++u) o[u] = f2bf(rv[it][u] * inv);
    *reinterpret_cast<us4*>(pb + it * 1024 + t * 4) = o;
  }
}

__global__ __launch_bounds__(256) void ag_pv_k(
    const float* __restrict__ sbuf, const u16* __restrict__ vg, float* __restrict__ obuf)
{
  int h = blockIdx.x;
  int kb0 = blockIdx.y * 256;
  int t = threadIdx.x;
  int w = t >> 6, lane = t & 63;
  int cl = lane & 15, g = lane >> 4;
  __shared__ u16 sVt[64 * 64];
  f32x4 zero4 = {0.f, 0.f, 0.f, 0.f};
  f32x4 O[4];
  #pragma unroll
  for (int dt = 0; dt < 4; ++dt) O[dt] = zero4;
  const u16* pb = (const u16*)(sbuf);
  int prow = w * 16 + cl;
  size_t pbase = (size_t)(h * 64 + prow) * 8192;

  for (int cc = 0; cc < 4; ++cc) {
    int kc = kb0 + cc * 64;
    #pragma unroll
    for (int it = 0; it < 2; ++it) {
      int idx = t + it * 256;
      int key = idx >> 3, d8 = idx & 7;
      us8 val = *reinterpret_cast<const us8*>(&vg[(size_t)(kc + key) * H + h * 64 + d8 * 8]);
      int k8 = key >> 3, klow = key & 7;
      int kswz = (k8 ^ d8) * 8 + klow;
      #pragma unroll
      for (int u = 0; u < 8; ++u)
        sVt[(d8 * 8 + u) * 64 + kswz] = val[u];
    }
    __syncthreads();
    #pragma unroll
    for (int ks = 0; ks < 2; ++ks) {
      bf16x8 pf = __builtin_bit_cast(bf16x8, *reinterpret_cast<const us8*>(
          pb + pbase + kc + (ks * 4 + g) * 8));
      #pragma unroll
      for (int dt = 0; dt < 4; ++dt) {
        int dim = dt * 16 + cl;
        int k8s = (ks * 4 + g) ^ ((dim >> 3) & 7);
        bf16x8 vf = __builtin_bit_cast(bf16x8, *reinterpret_cast<const us8*>(
            &sVt[dim * 64 + k8s * 8]));
        O[dt] = __builtin_amdgcn_mfma_f32_16x16x32_bf16(pf, vf, O[dt], 0, 0, 0);
      }
    }
    __syncthreads();
  }
  #pragma unroll
  for (int r = 0; r < 4; ++r) {
    int grow = w * 16 + g * 4 + r;
    #pragma unroll
    for (int dt = 0; dt < 4; ++dt)
      atomicAdd(&obuf[((size_t)h * 64 + grow) * 64 + dt * 16 + cl], O[dt][r]);
  }
}

__global__ __launch_bounds__(256) void ag_write_k(
    float* __restrict__ obuf, const int* __restrict__ gpos, u16* __restrict__ out)
{
  int g = blockIdx.x, t = threadIdx.x;
  int gp = gpos[g];
  if (gp < 0) gp = 0;
  if (gp >= LL) gp = LL - 1;
  #pragma unroll
  for (int e = 0; e < 3; ++e) {
    int c = t + e * 256;
    int h = c >> 6, d = c & 63;
    size_t idx = ((size_t)h * 64 + g) * 64 + d;
    out[(size_t)gp * H + c] = f2bf(obuf[idx]);
    obuf[idx] = 0.f;
  }
}

// ---------------- setup: isg + ginv + candidate positions + valid ----------------
__global__ void setup_k(const int* __restrict__ gpos, unsigned char* __restrict__ isg,
                        int* __restrict__ ginv,
                        const int* __restrict__ ids, const int* __restrict__ candp,
                        int* __restrict__ posb, float* __restrict__ outp) {
  int t = threadIdx.x;
  for (int i = t; i < LL; i += 256) { isg[i] = 0; ginv[i] = -1; }
  __syncthreads();
  if (t < GG) {
    int gp = gpos[t];
    if (gp >= 0 && gp < LL) { isg[gp] = 1; ginv[gp] = t; }
  }
  // candidate compaction
  int cand = candp[0];
  __shared__ int cnt[257];
  int base = t * 16, c0 = 0;
  for (int u = 0; u < 16; ++u) c0 += (ids[base + u] == cand) ? 1 : 0;
  cnt[t + 1] = c0;
  __syncthreads();
  if (t == 0) {
    cnt[0] = 0;
    for (int i2 = 1; i2 <= 256; ++i2) cnt[i2] += cnt[i2 - 1];
  }
  __syncthreads();
  int ncand = cnt[256];
  int cr = cnt[t];
  for (int u = 0; u < 16; ++u) {
    int i2 = base + u;
    bool isC = (ids[i2] == cand);
    if (isC) {
      if (cr < NCMAX) posb[cr] = i2;
      cr++;
    } else {
      int nc = i2 - cr;
      int slot = ncand + nc;
      if (slot < NCMAX && nc >= 0) posb[slot] = i2;
    }
  }
  if (t < NCMAX) outp[NCMAX + t] = (t < ncand) ? 1.f : 0.f;
}

__global__ __launch_bounds__(256) void head_k(
    const float* __restrict__ x, const int* __restrict__ posb,
    const float* __restrict__ Wh1, const float* __restrict__ bh1,
    const float* __restrict__ Wh2, const float* __restrict__ bh2, float* __restrict__ outp) {
  int s = blockIdx.x, t = threadIdx.x;
  int p = posb[s];
  if (p < 0) p = 0;
  if (p >= LL) p = LL - 1;
  __shared__ float sx[H];
  __shared__ float sh[384];
  __shared__ float red[4];
  #pragma unroll
  for (int e = 0; e < 3; ++e) sx[t + e * 256] = x[(size_t)p * H + t + e * 256];
  __syncthreads();
  for (int j = t; j < 384; j += 256) {
    float a = bh1[j];
    for (int c = 0; c < H; ++c) a += sx[c] * Wh1[(size_t)c * 384 + j];
    sh[j] = geluf(a);
  }
  __syncthreads();
  float part = 0.f;
  for (int j = t; j < 384; j += 256) part += sh[j] * Wh2[j];
  part = wredsum(part);
  if ((t & 63) == 0) red[t >> 6] = part;
  __syncthreads();
  if (t == 0) {
    float tot = red[0] + red[1] + red[2] + red[3] + bh2[0];
    outp[s] = tot;
  }
}

// ---------------- launch ----------------
extern "C" void kernel_launch(void* const* d_in, const int* in_sizes, int n_in,
                              void* d_out, int out_size, void* d_ws, size_t ws_size,
                              hipStream_t stream) {
  const float* emb_tok = (const float*)d_in[0];
  const float* emb_pos = (const float*)d_in[1];
  const float* lnes = (const float*)d_in[2];
  const float* lneb = (const float*)d_in[3];
  const float* Wq = (const float*)d_in[4];
  const float* bq = (const float*)d_in[5];
  const float* Wk = (const float*)d_in[6];
  const float* bk = (const float*)d_in[7];
  const float* Wv = (const float*)d_in[8];
  const float* bv = (const float*)d_in[9];
  const float* Wqg = (const float*)d_in[10];
  const float* bqg = (const float*)d_in[11];
  const float* Wkg = (const float*)d_in[12];
  const float* bkg = (const float*)d_in[13];
  const float* Wvg = (const float*)d_in[14];
  const float* bvg = (const float*)d_in[15];
  const float* Wo = (const float*)d_in[16];
  const float* bo = (const float*)d_in[17];
  const float* ln1s = (const float*)d_in[18];
  const float* ln1b = (const float*)d_in[19];
  const float* W1 = (const float*)d_in[20];
  const float* b1 = (const float*)d_in[21];
  const float* W2 = (const float*)d_in[22];
  const float* b2 = (const float*)d_in[23];
  const float* ln2s = (const float*)d_in[24];
  const float* ln2b = (const float*)d_in[25];
  const float* Wh1 = (const float*)d_in[26];
  const float* bh1 = (const float*)d_in[27];
  const float* Wh2 = (const float*)d_in[28];
  const float* bh2 = (const float*)d_in[29];
  const int* ids = (const int*)d_in[30];
  int i_gpos = 32, i_cand = 33;
  if (!(n_in >= 34 && in_sizes[32] == GG)) {
    if (n_in >= 33 && in_sizes[31] == GG) { i_gpos = 31; i_cand = 32; }
  }
  const int* gpos = (const int*)d_in[i_gpos];
  const int* cand = (const int*)d_in[i_cand];
  float* outp = (float*)d_out;

  char* p = (char*)d_ws;
  auto alloc = [&](size_t bytes) {
    char* r = p;
    p += (bytes + 255) & ~(size_t)255;
    return r;
  };
  float* x = (float*)alloc((size_t)LL * H * 4);
  u16* xb = (u16*)alloc((size_t)LL * H * 2);
  u16* qb = (u16*)alloc((size_t)LL * H * 2);   // hb aliases qb..kgb
  u16* kb = (u16*)alloc((size_t)LL * H * 2);
  u16* vb = (u16*)alloc((size_t)LL * H * 2);
  u16* kgb = (u16*)alloc((size_t)LL * H * 2);
  u16* vgb = (u16*)alloc((size_t)LL * H * 2);
  u16* ob = (u16*)alloc((size_t)LL * H * 2);
  u16* qgb = (u16*)alloc((size_t)GG * H * 2);
  u16* xgb = (u16*)alloc((size_t)128 * H * 2);
  unsigned char* isg = (unsigned char*)alloc(LL);
  int* ginv = (int*)alloc(LL * 4);
  int* posb = (int*)alloc(64 * 4);
  u16* wtb = (u16*)alloc((size_t)NL * WT_ELEMS * 2);
  float* sbuf = (float*)alloc((size_t)NH * 64 * 4096 * 4);
  float* obuf = (float*)alloc((size_t)NH * 64 * 64 * 4);
  float* partb = (float*)alloc((size_t)2 * LL * H * 4);
  u16* hb = qb;

  hipMemsetAsync(obuf, 0, (size_t)NH * 64 * 64 * 4, stream);

  setup_k<<<1, 256, 0, stream>>>(gpos, isg, ginv, ids, cand, posb, outp);
  conv_all_k<<<dim3(2160, NL), 256, 0, stream>>>(Wq, Wk, Wv, Wkg, Wvg, Wqg, Wo, W1, W2, wtb);
  embed_ln_k<<<LL, 256, 0, stream>>>(emb_tok, emb_pos, ids, lnes, lneb, ginv, x, xb, xgb);

  dim3 gP2(H / 128, LL / 128, 2);
  dim3 gF(FF / 128, LL / 128);
  dim3 gQKV(H / 128, LL / 128, 6);
  for (int l = 0; l < NL; ++l) {
    u16* wt = wtb + (size_t)l * WT_ELEMS;
    gemm_qkv_k<<<gQKV, 256, 0, stream>>>(xb, xgb, wt,
        bq + l * H, bk + l * H, bv + l * H, bkg + l * H, bvg + l * H, bqg + l * H,
        qb, kb, vb, kgb, vgb, qgb);
    attn_local_k<<<dim3(NH, LL / 64), 256, 0, stream>>>(qb, kb, vb, kgb, vgb, gpos, isg, ob);
    ag_score_k<<<dim3(NH, LL / 128), 256, 0, stream>>>(qgb, kgb, sbuf);
    ag_soft_k<<<NH * 64, 256, 0, stream>>>(sbuf);
    ag_pv_k<<<dim3(NH, LL / 256), 256, 0, stream>>>(sbuf, vgb, obuf);
    ag_write_k<<<GG, 256, 0, stream>>>(obuf, gpos, ob);
    gemm_part_k<<<gP2, 256, 0, stream>>>(ob, wt + OFF_O, partb, LL, H, H);
    ln_res2_k<2><<<LL, 256, 0, stream>>>(x, partb, bo + l * H, ln1s + l * H, ln1b + l * H, ginv, xb, xgb);
    gemm_bias_k<1><<<gF, 256, 0, stream>>>(xb, wt + OFF_W1, b1 + l * FF, hb, LL, FF, H);
    gemm_part_k<<<gP2, 256, 0, stream>>>(hb, wt + OFF_W2, partb, LL, H, FF);
    ln_res2_k<2><<<LL, 256, 0, stream>>>(x, partb, b2 + l * H, ln2s + l * H, ln2b + l * H, ginv, xb, xgb);
  }
  head_k<<<NCMAX, 256, 0, stream>>>(x, posb, Wh1, bh1, Wh2, bh2, outp);
}

// Round 13
// 1463.948 us; speedup vs baseline: 1.0137x; 1.0137x over previous
//
#include <hip/hip_runtime.h>
#include <hip/hip_bf16.h>
#include <math.h>

#define H 768
#define NH 12
#define DH 64
#define NL 6
#define FF 3072
#define LL 4096
#define GG 64
#define NCMAX 32

#define MATSZ (H * H)
#define OFF_QG ((size_t)5 * MATSZ)
#define OFF_O  ((size_t)6 * MATSZ)
#define OFF_W1 ((size_t)7 * MATSZ)
#define OFF_W2 (OFF_W1 + (size_t)H * FF)
#define WT_ELEMS (OFF_W2 + (size_t)FF * H)

typedef unsigned short u16;
typedef __attribute__((ext_vector_type(8))) unsigned short us8;
typedef __attribute__((ext_vector_type(4))) unsigned short us4;
typedef __attribute__((ext_vector_type(8))) __bf16 bf16x8;
typedef __attribute__((ext_vector_type(4))) float f32x4;

__device__ __forceinline__ float bf2f(u16 u) {
  unsigned v = ((unsigned)u) << 16;
  return __builtin_bit_cast(float, v);
}
__device__ __forceinline__ u16 f2bf(float f) {
  unsigned u = __builtin_bit_cast(unsigned, f);
  unsigned r = (u + 0x7fffu + ((u >> 16) & 1u)) >> 16;
  return (u16)r;
}
__device__ __forceinline__ float geluf(float a) {
  return 0.5f * a * (1.f + erff(a * 0.70710678118654752440f));
}
__device__ __forceinline__ float wredsum(float v) {
  #pragma unroll
  for (int o = 32; o; o >>= 1) v += __shfl_xor(v, o);
  return v;
}
__device__ __forceinline__ float wredmax(float v) {
  #pragma unroll
  for (int o = 32; o; o >>= 1) v = fmaxf(v, __shfl_xor(v, o));
  return v;
}
__device__ __forceinline__ void gld16(const u16* g, u16* l) {
  __builtin_amdgcn_global_load_lds(
      (const __attribute__((address_space(1))) unsigned int*)(const void*)g,
      (__attribute__((address_space(3))) unsigned int*)(void*)l, 16, 0, 0);
}
__device__ __forceinline__ void tswz(int& bx, int& by) {
  int nx = gridDim.x, ny = gridDim.y;
  int flat = blockIdx.y * nx + blockIdx.x;
  int nwg = nx * ny;
  if ((nwg & 7) == 0) {
    int c = nwg >> 3;
    flat = (flat & 7) * c + (flat >> 3);
  }
  bx = flat % nx;
  by = flat / nx;
}

// ---------------- embed + LN (writes xgb rows for global positions) ----------------
__global__ __launch_bounds__(256) void embed_ln_k(
    const float* __restrict__ et, const float* __restrict__ ep, const int* __restrict__ ids,
    const float* __restrict__ sc, const float* __restrict__ bi,
    const int* __restrict__ ginv,
    float* __restrict__ x, u16* __restrict__ xb, u16* __restrict__ xgb)
{
  int r = blockIdx.x, t = threadIdx.x;
  int tok = ids[r];
  if (tok < 0) tok = 0;
  if (tok >= 50272) tok = 50271;
  int gi = ginv[r];
  __shared__ float red[4];
  float v[3];
  #pragma unroll
  for (int e = 0; e < 3; ++e) {
    int c = t + e * 256;
    v[e] = et[(size_t)tok * H + c] + ep[(size_t)r * H + c];
  }
  float s = v[0] + v[1] + v[2];
  s = wredsum(s);
  if ((t & 63) == 0) red[t >> 6] = s;
  __syncthreads();
  float mean = (red[0] + red[1] + red[2] + red[3]) * (1.f / 768.f);
  __syncthreads();
  float q = 0.f;
  #pragma unroll
  for (int e = 0; e < 3; ++e) { float d = v[e] - mean; q += d * d; }
  q = wredsum(q);
  if ((t & 63) == 0) red[t >> 6] = q;
  __syncthreads();
  float var = (red[0] + red[1] + red[2] + red[3]) * (1.f / 768.f);
  float rs = rsqrtf(var + 1e-5f);
  #pragma unroll
  for (int e = 0; e < 3; ++e) {
    int c = t + e * 256;
    float o = (v[e] - mean) * rs * sc[c] + bi[c];
    x[(size_t)r * H + c] = o;
    u16 ob16 = f2bf(o);
    xb[(size_t)r * H + c] = ob16;
    if (gi >= 0) xgb[(size_t)gi * H + c] = ob16;
  }
}

// ---------------- LN over x + bias + sum of Z partial buffers ----------------
template<int Z>
__global__ __launch_bounds__(256) void ln_res2_k(
    float* __restrict__ x, const float* __restrict__ part, const float* __restrict__ bias,
    const float* __restrict__ sc, const float* __restrict__ bi,
    const int* __restrict__ ginv, u16* __restrict__ xb, u16* __restrict__ xgb)
{
  int r = blockIdx.x, t = threadIdx.x;
  int gi = ginv[r];
  __shared__ float red[4];
  float v[3];
  #pragma unroll
  for (int e = 0; e < 3; ++e) {
    int c = t + e * 256;
    float a = x[(size_t)r * H + c] + bias[c];
    #pragma unroll
    for (int z = 0; z < Z; ++z)
      a += part[(size_t)z * LL * H + (size_t)r * H + c];
    v[e] = a;
  }
  float s = v[0] + v[1] + v[2];
  s = wredsum(s);
  if ((t & 63) == 0) red[t >> 6] = s;
  __syncthreads();
  float mean = (red[0] + red[1] + red[2] + red[3]) * (1.f / 768.f);
  __syncthreads();
  float q = 0.f;
  #pragma unroll
  for (int e = 0; e < 3; ++e) { float d = v[e] - mean; q += d * d; }
  q = wredsum(q);
  if ((t & 63) == 0) red[t >> 6] = q;
  __syncthreads();
  float var = (red[0] + red[1] + red[2] + red[3]) * (1.f / 768.f);
  float rs = rsqrtf(var + 1e-5f);
  #pragma unroll
  for (int e = 0; e < 3; ++e) {
    int c = t + e * 256;
    float o = (v[e] - mean) * rs * sc[c] + bi[c];
    x[(size_t)r * H + c] = o;
    u16 ob16 = f2bf(o);
    xb[(size_t)r * H + c] = ob16;
    if (gi >= 0) xgb[(size_t)gi * H + c] = ob16;
  }
}

// ---------------- all-layers weight convert+transpose (64k x 128n tiles) ----------------
// per layer: 7*72 + 288 + 288 = 1080 blocks; grid (1080, NL)
__global__ __launch_bounds__(256) void conv_all_k(
    const float* __restrict__ Wq, const float* __restrict__ Wk, const float* __restrict__ Wv,
    const float* __restrict__ Wkg, const float* __restrict__ Wvg, const float* __restrict__ Wqg,
    const float* __restrict__ Wo, const float* __restrict__ W1, const float* __restrict__ W2,
    u16* __restrict__ wt)
{
  int l = blockIdx.y;
  int bid = blockIdx.x, t = threadIdx.x;
  size_t lo = (size_t)l * MATSZ;
  size_t lf = (size_t)l * H * FF;
  u16* wto = wt + (size_t)l * WT_ELEMS;
  const float* src;
  size_t ooff;
  int K, N, tile;
  if (bid < 504) {
    int m = bid / 72;
    tile = bid % 72;
    K = H; N = H;
    ooff = (size_t)m * MATSZ;
    src = (m == 0 ? Wq : m == 1 ? Wk : m == 2 ? Wv : m == 3 ? Wkg : m == 4 ? Wvg : m == 5 ? Wqg : Wo) + lo;
  } else if (bid < 792) {
    tile = bid - 504;
    K = H; N = FF;
    ooff = OFF_W1;
    src = W1 + lf;
  } else {
    tile = bid - 792;
    K = FF; N = H;
    ooff = OFF_W2;
    src = W2 + lf;
  }
  int KT = K / 64;
  int kt = tile % KT, nt = tile / KT;
  __shared__ u16 sT[128 * 66];   // [n_local][k], 132B stride
  #pragma unroll
  for (int it = 0; it < 8; ++it) {
    int idx = t + it * 256;
    int kk = idx >> 5, q = idx & 31;
    f32x4 val = *reinterpret_cast<const f32x4*>(
        &src[(size_t)(kt * 64 + kk) * N + nt * 128 + q * 4]);
    #pragma unroll
    for (int u = 0; u < 4; ++u)
      sT[(q * 4 + u) * 66 + kk] = f2bf(val[u]);
  }
  __syncthreads();
  #pragma unroll
  for (int it = 0; it < 4; ++it) {
    int idx = t + it * 256;
    int n = idx >> 3, k8 = idx & 7;
    const u16* base = &sT[n * 66 + k8 * 8];
    us8 val;
    unsigned* vp = reinterpret_cast<unsigned*>(&val);
    #pragma unroll
    for (int j = 0; j < 4; ++j)
      vp[j] = *reinterpret_cast<const unsigned*>(base + j * 2);
    *reinterpret_cast<us8*>(&wto[ooff + (size_t)(nt * 128 + n) * K + kt * 64 + k8 * 8]) = val;
  }
}

// ---- GEMM K-loop core (async global_load_lds staging) ----
__device__ __forceinline__ void gemm_loop(
    const u16* __restrict__ A, const u16* __restrict__ Bt,
    int K, int m0, int n0, int kb, int ke,
    u16* lsA, u16* lsB, f32x4 acc[4][4])
{
  int t = threadIdx.x;
  int w = t >> 6, lane = t & 63;
  int cl = lane & 15, kgr = lane >> 4;
  int wm = (w >> 1) * 64, wn = (w & 1) * 64;
  for (int k0 = kb; k0 < ke; k0 += 64) {
    int ml = lane >> 3, k8 = lane & 7;
    #pragma unroll
    for (int it = 0; it < 4; ++it) {
      int chunk = it * 4 + w;
      int m = chunk * 8 + ml;
      gld16(A + (size_t)(m0 + m) * K + k0 + ((k8 ^ (m & 7)) * 8),
            &lsA[chunk * 512 + lane * 8]);
    }
    #pragma unroll
    for (int it = 0; it < 4; ++it) {
      int chunk = it * 4 + w;
      int n = chunk * 8 + ml;
      gld16(Bt + (size_t)(n0 + n) * K + k0 + ((k8 ^ (n & 7)) * 8),
            &lsB[chunk * 512 + lane * 8]);
    }
    __syncthreads();
    #pragma unroll
    for (int kk = 0; kk < 2; ++kk) {
      bf16x8 fa[4], fb[4];
      int k8r = kk * 4 + kgr;
      #pragma unroll
      for (int i = 0; i < 4; ++i) {
        int mr = wm + i * 16 + cl;
        fa[i] = __builtin_bit_cast(bf16x8,
            *reinterpret_cast<const us8*>(&lsA[mr * 64 + ((k8r ^ (mr & 7)) * 8)]));
        int nr = wn + i * 16 + cl;
        fb[i] = __builtin_bit_cast(bf16x8,
            *reinterpret_cast<const us8*>(&lsB[nr * 64 + ((k8r ^ (nr & 7)) * 8)]));
      }
      #pragma unroll
      for (int i = 0; i < 4; ++i)
        #pragma unroll
        for (int j = 0; j < 4; ++j)
          acc[i][j] = __builtin_amdgcn_mfma_f32_16x16x32_bf16(fa[i], fb[j], acc[i][j], 0, 0, 0);
    }
    __syncthreads();
  }
}

template<int ACT>
__global__ __launch_bounds__(256) void gemm_bias_k(
    const u16* __restrict__ A, const u16* __restrict__ Bt, const float* __restrict__ bias,
    u16* __restrict__ outB, int M, int N, int K)
{
  __shared__ u16 lsA[128 * 64];
  __shared__ u16 lsB[128 * 64];
  int bx, by;
  tswz(bx, by);
  int m0 = by * 128, n0 = bx * 128;
  f32x4 zero4 = {0.f, 0.f, 0.f, 0.f};
  f32x4 acc[4][4];
  #pragma unroll
  for (int i = 0; i < 4; ++i)
    #pragma unroll
    for (int j = 0; j < 4; ++j) acc[i][j] = zero4;
  gemm_loop(A, Bt, K, m0, n0, 0, K, lsA, lsB, acc);
  int lane = threadIdx.x & 63, w = threadIdx.x >> 6;
  int cl = lane & 15, kgr = lane >> 4;
  int wm = (w >> 1) * 64, wn = (w & 1) * 64;
  #pragma unroll
  for (int j = 0; j < 4; ++j) {
    int n = n0 + wn + j * 16 + cl;
    float bv = bias[n];
    #pragma unroll
    for (int i = 0; i < 4; ++i) {
      #pragma unroll
      for (int r = 0; r < 4; ++r) {
        int m = m0 + wm + i * 16 + kgr * 4 + r;
        if (m < M) {
          float vv = acc[i][j][r] + bv;
          if (ACT == 1) vv = geluf(vv);
          outB[(size_t)m * N + n] = f2bf(vv);
        }
      }
    }
  }
}

__global__ __launch_bounds__(256) void gemm_part_k(
    const u16* __restrict__ A, const u16* __restrict__ Bt, float* __restrict__ part,
    int M, int N, int K)
{
  __shared__ u16 lsA[128 * 64];
  __shared__ u16 lsB[128 * 64];
  int bx, by;
  tswz(bx, by);
  int m0 = by * 128, n0 = bx * 128;
  int z = blockIdx.z, ns = gridDim.z;
  int ks = K / ns;
  f32x4 zero4 = {0.f, 0.f, 0.f, 0.f};
  f32x4 acc[4][4];
  #pragma unroll
  for (int i = 0; i < 4; ++i)
    #pragma unroll
    for (int j = 0; j < 4; ++j) acc[i][j] = zero4;
  gemm_loop(A, Bt, K, m0, n0, z * ks, (z + 1) * ks, lsA, lsB, acc);
  int lane = threadIdx.x & 63, w = threadIdx.x >> 6;
  int cl = lane & 15, kgr = lane >> 4;
  int wm = (w >> 1) * 64, wn = (w & 1) * 64;
  float* po = part + (size_t)z * LL * H;
  #pragma unroll
  for (int j = 0; j < 4; ++j) {
    int n = n0 + wn + j * 16 + cl;
    #pragma unroll
    for (int i = 0; i < 4; ++i) {
      #pragma unroll
      for (int r = 0; r < 4; ++r) {
        int m = m0 + wm + i * 16 + kgr * 4 + r;
        po[(size_t)m * N + n] = acc[i][j][r];
      }
    }
  }
}

// fused 6-way projection GEMM: z<5 -> (q,k,v,kg,vg) from xb; z==5 -> qg from xgb
__global__ __launch_bounds__(256) void gemm_qkv_k(
    const u16* __restrict__ A, const u16* __restrict__ Ag, const u16* __restrict__ wt,
    const float* c0, const float* c1, const float* c2, const float* c3, const float* c4,
    const float* c5,
    u16* o0, u16* o1, u16* o2, u16* o3, u16* o4, u16* o5)
{
  __shared__ u16 lsA[128 * 64];
  __shared__ u16 lsB[128 * 64];
  int z = blockIdx.z;
  int bx, by;
  tswz(bx, by);
  if (z == 5 && by != 0) return;
  const u16* Bt = wt + (size_t)z * MATSZ;
  const float* bias = z == 0 ? c0 : z == 1 ? c1 : z == 2 ? c2 : z == 3 ? c3 : z == 4 ? c4 : c5;
  u16* outB = z == 0 ? o0 : z == 1 ? o1 : z == 2 ? o2 : z == 3 ? o3 : z == 4 ? o4 : o5;
  const u16* Ap = (z == 5) ? Ag : A;
  int M = (z == 5) ? GG : LL;
  int m0 = by * 128, n0 = bx * 128;
  f32x4 zero4 = {0.f, 0.f, 0.f, 0.f};
  f32x4 acc[4][4];
  #pragma unroll
  for (int i = 0; i < 4; ++i)
    #pragma unroll
    for (int j = 0; j < 4; ++j) acc[i][j] = zero4;
  gemm_loop(Ap, Bt, H, m0, n0, 0, H, lsA, lsB, acc);
  int lane = threadIdx.x & 63, w = threadIdx.x >> 6;
  int cl = lane & 15, kgr = lane >> 4;
  int wm = (w >> 1) * 64, wn = (w & 1) * 64;
  #pragma unroll
  for (int j = 0; j < 4; ++j) {
    int n = n0 + wn + j * 16 + cl;
    float bv = bias[n];
    #pragma unroll
    for (int i = 0; i < 4; ++i) {
      #pragma unroll
      for (int r = 0; r < 4; ++r) {
        int m = m0 + wm + i * 16 + kgr * 4 + r;
        if (m < M) outB[(size_t)m * H + n] = f2bf(acc[i][j][r] + bv);
      }
    }
  }
}

// ---------------- MFMA flash local attention (double-buffered, 1 barrier/chunk) ----------------
__global__ __launch_bounds__(256) void attn_local_k(
    const u16* __restrict__ q, const u16* __restrict__ k, const u16* __restrict__ v,
    const u16* __restrict__ kgp, const u16* __restrict__ vgp,
    const int* __restrict__ gpos, const unsigned char* __restrict__ isg,
    u16* __restrict__ out)
{
  int h = blockIdx.x;
  int q0 = blockIdx.y * 64;
  int nb = q0 >> 8;
  int cs = (nb - 1) * 256;
  int cstart = (q0 >> 6) & 3;
  int t = threadIdx.x;
  int w = t >> 6, lane = t & 63;
  int cl = lane & 15, g = lane >> 4;
  __shared__ u16 sKb[2][64 * 64];
  __shared__ u16 sVtb[2][64 * 64];
  __shared__ u16 sP[64 * 64];
  __shared__ unsigned char sOkb[2][64];
  us8 z8 = {0, 0, 0, 0, 0, 0, 0, 0};
  f32x4 zero4 = {0.f, 0.f, 0.f, 0.f};

  int qrow = q0 + w * 16 + cl;
  bf16x8 qa[2];
  #pragma unroll
  for (int ks = 0; ks < 2; ++ks)
    qa[ks] = __builtin_bit_cast(bf16x8, *reinterpret_cast<const us8*>(
        &q[(size_t)qrow * H + h * 64 + ks * 32 + g * 8]));

  f32x4 O[4];
  #pragma unroll
  for (int dt = 0; dt < 4; ++dt) O[dt] = zero4;
  float mrow[4], lrow[4];
  #pragma unroll
  for (int r = 0; r < 4; ++r) { mrow[r] = -1e30f; lrow[r] = 0.f; }

  // stage(ci, buf): async K via gld16; V reg-staged transposed; ok flags
  auto stage = [&](int ci, int buf) {
    bool isLocal = (ci < 9);
    int kbase = cs + (cstart + ci) * 64;
    #pragma unroll
    for (int it = 0; it < 2; ++it) {
      int idx = it * 256 + t;
      int key = idx >> 3, d8 = idx & 7;
      int pos;
      if (isLocal) {
        pos = kbase + key;
        pos = pos < 0 ? 0 : (pos >= LL ? LL - 1 : pos);
      } else {
        pos = gpos[key];
        pos = pos < 0 ? 0 : (pos >= LL ? LL - 1 : pos);
      }
      const u16* src = (isLocal ? k : kgp) + (size_t)pos * H + h * 64 + ((d8 ^ (key & 7)) * 8);
      gld16(src, &sKb[buf][idx * 8]);
    }
    #pragma unroll
    for (int it = 0; it < 2; ++it) {
      int idx = t + it * 256;
      int key = idx >> 3, d8 = idx & 7;
      us8 val = z8;
      if (isLocal) {
        int pos = kbase + key;
        if (pos >= 0 && pos < LL)
          val = *reinterpret_cast<const us8*>(&v[(size_t)pos * H + h * 64 + d8 * 8]);
      } else {
        int pos = gpos[key];
        if (pos < 0) pos = 0;
        if (pos >= LL) pos = LL - 1;
        val = *reinterpret_cast<const us8*>(&vgp[(size_t)pos * H + h * 64 + d8 * 8]);
      }
      int k8 = key >> 3, klow = key & 7;
      int kswz = (k8 ^ d8) * 8 + klow;
      #pragma unroll
      for (int u = 0; u < 8; ++u)
        sVtb[buf][(d8 * 8 + u) * 64 + kswz] = val[u];
    }
    if (t < 64) {
      int ok = 1;
      if (isLocal) {
        int pos = kbase + t;
        ok = (pos >= 0 && pos < LL) ? (isg[pos] ? 0 : 1) : 0;
      }
      sOkb[buf][t] = (unsigned char)ok;
    }
  };

  stage(0, 0);
  int buf = 0;
  for (int ci = 0; ci < 10; ++ci) {
    __syncthreads();            // stage(ci) visible; prev compute reads done
    if (ci < 9) stage(ci + 1, buf ^ 1);
    bool isLocal = (ci < 9);
    int kbase = cs + (cstart + ci) * 64;
    const u16* sK = sKb[buf];
    const u16* sVt = sVtb[buf];
    const unsigned char* sOk = sOkb[buf];

    f32x4 S[4];
    #pragma unroll
    for (int T = 0; T < 4; ++T) {
      S[T] = zero4;
      int key = T * 16 + cl;
      #pragma unroll
      for (int ks = 0; ks < 2; ++ks) {
        bf16x8 kf = __builtin_bit_cast(bf16x8, *reinterpret_cast<const us8*>(
            &sK[key * 64 + (((ks * 4 + g) ^ (key & 7)) * 8)]));
        S[T] = __builtin_amdgcn_mfma_f32_16x16x32_bf16(qa[ks], kf, S[T], 0, 0, 0);
      }
    }
    #pragma unroll
    for (int T = 0; T < 4; ++T) {
      int key = T * 16 + cl;
      int okk = sOk[key];
      int pos = kbase + key;
      #pragma unroll
      for (int r = 0; r < 4; ++r) {
        int qp = q0 + w * 16 + g * 4 + r;
        int d = pos - qp;
        bool ok = okk && (!isLocal || (d >= -256 && d <= 256));
        S[T][r] = ok ? S[T][r] * 0.125f : -1e9f;
      }
    }
    float cm[4];
    #pragma unroll
    for (int r = 0; r < 4; ++r) {
      cm[r] = fmaxf(fmaxf(S[0][r], S[1][r]), fmaxf(S[2][r], S[3][r]));
      cm[r] = fmaxf(cm[r], __shfl_xor(cm[r], 1));
      cm[r] = fmaxf(cm[r], __shfl_xor(cm[r], 2));
      cm[r] = fmaxf(cm[r], __shfl_xor(cm[r], 4));
      cm[r] = fmaxf(cm[r], __shfl_xor(cm[r], 8));
    }
    float sc[4];
    #pragma unroll
    for (int r = 0; r < 4; ++r) {
      float mn = fmaxf(mrow[r], cm[r]);
      sc[r] = __expf(mrow[r] - mn);
      mrow[r] = mn;
    }
    float rs[4] = {0.f, 0.f, 0.f, 0.f};
    #pragma unroll
    for (int T = 0; T < 4; ++T) {
      int key = T * 16 + cl;
      #pragma unroll
      for (int r = 0; r < 4; ++r) {
        float sv = S[T][r];
        float pv = sv > -1e8f ? __expf(sv - mrow[r]) : 0.f;
        rs[r] += pv;
        int qloc = w * 16 + g * 4 + r;
        int k8s = (key >> 3) ^ (qloc & 7);
        sP[qloc * 64 + k8s * 8 + (key & 7)] = f2bf(pv);
      }
    }
    #pragma unroll
    for (int r = 0; r < 4; ++r) {
      rs[r] += __shfl_xor(rs[r], 1);
      rs[r] += __shfl_xor(rs[r], 2);
      rs[r] += __shfl_xor(rs[r], 4);
      rs[r] += __shfl_xor(rs[r], 8);
      lrow[r] = lrow[r] * sc[r] + rs[r];
    }
    #pragma unroll
    for (int dt = 0; dt < 4; ++dt)
      #pragma unroll
      for (int r = 0; r < 4; ++r) O[dt][r] *= sc[r];
    int prow = w * 16 + cl;
    #pragma unroll
    for (int ks = 0; ks < 2; ++ks) {
      bf16x8 pf = __builtin_bit_cast(bf16x8, *reinterpret_cast<const us8*>(
          &sP[prow * 64 + (((ks * 4 + g) ^ (prow & 7)) * 8)]));
      #pragma unroll
      for (int dt = 0; dt < 4; ++dt) {
        int dim = dt * 16 + cl;
        int k8s = (ks * 4 + g) ^ ((dim >> 3) & 7);
        bf16x8 vf = __builtin_bit_cast(bf16x8, *reinterpret_cast<const us8*>(
            &sVt[dim * 64 + k8s * 8]));
        O[dt] = __builtin_amdgcn_mfma_f32_16x16x32_bf16(pf, vf, O[dt], 0, 0, 0);
      }
    }
    buf ^= 1;
  }
  #pragma unroll
  for (int r = 0; r < 4; ++r) {
    float inv = 1.f / lrow[r];
    int qp = q0 + w * 16 + g * 4 + r;
    #pragma unroll
    for (int dt = 0; dt < 4; ++dt)
      out[(size_t)qp * H + h * 64 + dt * 16 + cl] = f2bf(O[dt][r] * inv);
  }
}

// ---------------- global attention (wide 4-kernel pipeline) ----------------
__global__ __launch_bounds__(256) void ag_score_k(
    const u16* __restrict__ qg, const u16* __restrict__ kg, float* __restrict__ sbuf)
{
  int h = blockIdx.x;
  int kc0 = blockIdx.y * 128;
  int t = threadIdx.x;
  int w = t >> 6, lane = t & 63;
  int cl = lane & 15, g = lane >> 4;
  __shared__ u16 sK[128 * 64];
  #pragma unroll
  for (int it = 0; it < 4; ++it) {
    int idx = it * 256 + t;
    int key = idx >> 3, d8 = idx & 7;
    gld16(kg + (size_t)(kc0 + key) * H + h * 64 + ((d8 ^ (key & 7)) * 8), &sK[idx * 8]);
  }
  int qrow = w * 16 + cl;
  bf16x8 qa[2];
  #pragma unroll
  for (int ks = 0; ks < 2; ++ks)
    qa[ks] = __builtin_bit_cast(bf16x8, *reinterpret_cast<const us8*>(
        &qg[(size_t)qrow * H + h * 64 + ks * 32 + g * 8]));
  __syncthreads();
  f32x4 zero4 = {0.f, 0.f, 0.f, 0.f};
  #pragma unroll
  for (int j = 0; j < 8; ++j) {
    f32x4 S = zero4;
    int key = j * 16 + cl;
    #pragma unroll
    for (int ks = 0; ks < 2; ++ks) {
      bf16x8 kf = __builtin_bit_cast(bf16x8, *reinterpret_cast<const us8*>(
          &sK[key * 64 + (((ks * 4 + g) ^ (key & 7)) * 8)]));
      S = __builtin_amdgcn_mfma_f32_16x16x32_bf16(qa[ks], kf, S, 0, 0, 0);
    }
    #pragma unroll
    for (int r = 0; r < 4; ++r) {
      int grow = w * 16 + g * 4 + r;
      sbuf[((size_t)(h * 64 + grow)) * 4096 + kc0 + key] = S[r] * 0.125f;
    }
  }
}

__global__ __launch_bounds__(256) void ag_soft_k(float* __restrict__ sbuf)
{
  int row = blockIdx.x, t = threadIdx.x;
  float* base = sbuf + (size_t)row * 4096;
  u16* pb = (u16*)(sbuf) + (size_t)row * 8192;
  __shared__ float red[4];
  f32x4 rv[4];
  #pragma unroll
  for (int it = 0; it < 4; ++it)
    rv[it] = *reinterpret_cast<const f32x4*>(base + it * 1024 + t * 4);
  float m = -1e30f;
  #pragma unroll
  for (int it = 0; it < 4; ++it)
    #pragma unroll
    for (int u = 0; u < 4; ++u) m = fmaxf(m, rv[it][u]);
  m = wredmax(m);
  if ((t & 63) == 0) red[t >> 6] = m;
  __syncthreads();
  m = fmaxf(fmaxf(red[0], red[1]), fmaxf(red[2], red[3]));
  __syncthreads();
  float s = 0.f;
  #pragma unroll
  for (int it = 0; it < 4; ++it)
    #pragma unroll
    for (int u = 0; u < 4; ++u) {
      float e = __expf(rv[it][u] - m);
      rv[it][u] = e;
      s += e;
    }
  s = wredsum(s);
  if ((t & 63) == 0) red[t >> 6] = s;
  __syncthreads();
  float inv = 1.f / (red[0] + red[1] + red[2] + red[3]);
  #pragma unroll
  for (int it = 0; it < 4; ++it) {
    us4 o;
    #pragma unroll
    for (int u = 0; u < 4; ++u) o[u] = f2bf(rv[it][u] * inv);
    *reinterpret_cast<us4*>(pb + it * 1024 + t * 4) = o;
  }
}

__global__ __launch_bounds__(256) void ag_pv_k(
    const float* __restrict__ sbuf, const u16* __restrict__ vg, float* __restrict__ obuf)
{
  int h = blockIdx.x;
  int kb0 = blockIdx.y * 256;
  int t = threadIdx.x;
  int w = t >> 6, lane = t & 63;
  int cl = lane & 15, g = lane >> 4;
  __shared__ u16 sVt[64 * 64];
  f32x4 zero4 = {0.f, 0.f, 0.f, 0.f};
  f32x4 O[4];
  #pragma unroll
  for (int dt = 0; dt < 4; ++dt) O[dt] = zero4;
  const u16* pb = (const u16*)(sbuf);
  int prow = w * 16 + cl;
  size_t pbase = (size_t)(h * 64 + prow) * 8192;

  for (int cc = 0; cc < 4; ++cc) {
    int kc = kb0 + cc * 64;
    #pragma unroll
    for (int it = 0; it < 2; ++it) {
      int idx = t + it * 256;
      int key = idx >> 3, d8 = idx & 7;
      us8 val = *reinterpret_cast<const us8*>(&vg[(size_t)(kc + key) * H + h * 64 + d8 * 8]);
      int k8 = key >> 3, klow = key & 7;
      int kswz = (k8 ^ d8) * 8 + klow;
      #pragma unroll
      for (int u = 0; u < 8; ++u)
        sVt[(d8 * 8 + u) * 64 + kswz] = val[u];
    }
    __syncthreads();
    #pragma unroll
    for (int ks = 0; ks < 2; ++ks) {
      bf16x8 pf = __builtin_bit_cast(bf16x8, *reinterpret_cast<const us8*>(
          pb + pbase + kc + (ks * 4 + g) * 8));
      #pragma unroll
      for (int dt = 0; dt < 4; ++dt) {
        int dim = dt * 16 + cl;
        int k8s = (ks * 4 + g) ^ ((dim >> 3) & 7);
        bf16x8 vf = __builtin_bit_cast(bf16x8, *reinterpret_cast<const us8*>(
            &sVt[dim * 64 + k8s * 8]));
        O[dt] = __builtin_amdgcn_mfma_f32_16x16x32_bf16(pf, vf, O[dt], 0, 0, 0);
      }
    }
    __syncthreads();
  }
  #pragma unroll
  for (int r = 0; r < 4; ++r) {
    int grow = w * 16 + g * 4 + r;
    #pragma unroll
    for (int dt = 0; dt < 4; ++dt)
      atomicAdd(&obuf[((size_t)h * 64 + grow) * 64 + dt * 16 + cl], O[dt][r]);
  }
}

__global__ __launch_bounds__(256) void ag_write_k(
    float* __restrict__ obuf, const int* __restrict__ gpos, u16* __restrict__ out)
{
  int g = blockIdx.x, t = threadIdx.x;
  int gp = gpos[g];
  if (gp < 0) gp = 0;
  if (gp >= LL) gp = LL - 1;
  #pragma unroll
  for (int e = 0; e < 3; ++e) {
    int c = t + e * 256;
    int h = c >> 6, d = c & 63;
    size_t idx = ((size_t)h * 64 + g) * 64 + d;
    out[(size_t)gp * H + c] = f2bf(obuf[idx]);
    obuf[idx] = 0.f;
  }
}

// ---------------- setup: isg + ginv + candidate positions + valid ----------------
__global__ void setup_k(const int* __restrict__ gpos, unsigned char* __restrict__ isg,
                        int* __restrict__ ginv,
                        const int* __restrict__ ids, const int* __restrict__ candp,
                        int* __restrict__ posb, float* __restrict__ outp) {
  int t = threadIdx.x;
  for (int i = t; i < LL; i += 256) { isg[i] = 0; ginv[i] = -1; }
  __syncthreads();
  if (t < GG) {
    int gp = gpos[t];
    if (gp >= 0 && gp < LL) { isg[gp] = 1; ginv[gp] = t; }
  }
  int cand = candp[0];
  __shared__ int cnt[257];
  int base = t * 16, c0 = 0;
  for (int u = 0; u < 16; ++u) c0 += (ids[base + u] == cand) ? 1 : 0;
  cnt[t + 1] = c0;
  __syncthreads();
  if (t == 0) {
    cnt[0] = 0;
    for (int i2 = 1; i2 <= 256; ++i2) cnt[i2] += cnt[i2 - 1];
  }
  __syncthreads();
  int ncand = cnt[256];
  int cr = cnt[t];
  for (int u = 0; u < 16; ++u) {
    int i2 = base + u;
    bool isC = (ids[i2] == cand);
    if (isC) {
      if (cr < NCMAX) posb[cr] = i2;
      cr++;
    } else {
      int nc = i2 - cr;
      int slot = ncand + nc;
      if (slot < NCMAX && nc >= 0) posb[slot] = i2;
    }
  }
  if (t < NCMAX) outp[NCMAX + t] = (t < ncand) ? 1.f : 0.f;
}

__global__ __launch_bounds__(256) void head_k(
    const float* __restrict__ x, const int* __restrict__ posb,
    const float* __restrict__ Wh1, const float* __restrict__ bh1,
    const float* __restrict__ Wh2, const float* __restrict__ bh2, float* __restrict__ outp) {
  int s = blockIdx.x, t = threadIdx.x;
  int p = posb[s];
  if (p < 0) p = 0;
  if (p >= LL) p = LL - 1;
  __shared__ float sx[H];
  __shared__ float sh[384];
  __shared__ float red[4];
  #pragma unroll
  for (int e = 0; e < 3; ++e) sx[t + e * 256] = x[(size_t)p * H + t + e * 256];
  __syncthreads();
  for (int j = t; j < 384; j += 256) {
    float a = bh1[j];
    for (int c = 0; c < H; ++c) a += sx[c] * Wh1[(size_t)c * 384 + j];
    sh[j] = geluf(a);
  }
  __syncthreads();
  float part = 0.f;
  for (int j = t; j < 384; j += 256) part += sh[j] * Wh2[j];
  part = wredsum(part);
  if ((t & 63) == 0) red[t >> 6] = part;
  __syncthreads();
  if (t == 0) {
    float tot = red[0] + red[1] + red[2] + red[3] + bh2[0];
    outp[s] = tot;
  }
}

// ---------------- launch ----------------
extern "C" void kernel_launch(void* const* d_in, const int* in_sizes, int n_in,
                              void* d_out, int out_size, void* d_ws, size_t ws_size,
                              hipStream_t stream) {
  const float* emb_tok = (const float*)d_in[0];
  const float* emb_pos = (const float*)d_in[1];
  const float* lnes = (const float*)d_in[2];
  const float* lneb = (const float*)d_in[3];
  const float* Wq = (const float*)d_in[4];
  const float* bq = (const float*)d_in[5];
  const float* Wk = (const float*)d_in[6];
  const float* bk = (const float*)d_in[7];
  const float* Wv = (const float*)d_in[8];
  const float* bv = (const float*)d_in[9];
  const float* Wqg = (const float*)d_in[10];
  const float* bqg = (const float*)d_in[11];
  const float* Wkg = (const float*)d_in[12];
  const float* bkg = (const float*)d_in[13];
  const float* Wvg = (const float*)d_in[14];
  const float* bvg = (const float*)d_in[15];
  const float* Wo = (const float*)d_in[16];
  const float* bo = (const float*)d_in[17];
  const float* ln1s = (const float*)d_in[18];
  const float* ln1b = (const float*)d_in[19];
  const float* W1 = (const float*)d_in[20];
  const float* b1 = (const float*)d_in[21];
  const float* W2 = (const float*)d_in[22];
  const float* b2 = (const float*)d_in[23];
  const float* ln2s = (const float*)d_in[24];
  const float* ln2b = (const float*)d_in[25];
  const float* Wh1 = (const float*)d_in[26];
  const float* bh1 = (const float*)d_in[27];
  const float* Wh2 = (const float*)d_in[28];
  const float* bh2 = (const float*)d_in[29];
  const int* ids = (const int*)d_in[30];
  int i_gpos = 32, i_cand = 33;
  if (!(n_in >= 34 && in_sizes[32] == GG)) {
    if (n_in >= 33 && in_sizes[31] == GG) { i_gpos = 31; i_cand = 32; }
  }
  const int* gpos = (const int*)d_in[i_gpos];
  const int* cand = (const int*)d_in[i_cand];
  float* outp = (float*)d_out;

  char* p = (char*)d_ws;
  auto alloc = [&](size_t bytes) {
    char* r = p;
    p += (bytes + 255) & ~(size_t)255;
    return r;
  };
  float* x = (float*)alloc((size_t)LL * H * 4);
  u16* xb = (u16*)alloc((size_t)LL * H * 2);
  u16* qb = (u16*)alloc((size_t)LL * H * 2);   // hb aliases qb..kgb
  u16* kb = (u16*)alloc((size_t)LL * H * 2);
  u16* vb = (u16*)alloc((size_t)LL * H * 2);
  u16* kgb = (u16*)alloc((size_t)LL * H * 2);
  u16* vgb = (u16*)alloc((size_t)LL * H * 2);
  u16* ob = (u16*)alloc((size_t)LL * H * 2);
  u16* qgb = (u16*)alloc((size_t)GG * H * 2);
  u16* xgb = (u16*)alloc((size_t)128 * H * 2);
  unsigned char* isg = (unsigned char*)alloc(LL);
  int* ginv = (int*)alloc(LL * 4);
  int* posb = (int*)alloc(64 * 4);
  u16* wtb = (u16*)alloc((size_t)NL * WT_ELEMS * 2);
  float* sbuf = (float*)alloc((size_t)NH * 64 * 4096 * 4);
  float* obuf = (float*)alloc((size_t)NH * 64 * 64 * 4);
  float* partb = (float*)alloc((size_t)4 * LL * H * 4);
  u16* hb = qb;

  hipMemsetAsync(obuf, 0, (size_t)NH * 64 * 64 * 4, stream);

  setup_k<<<1, 256, 0, stream>>>(gpos, isg, ginv, ids, cand, posb, outp);
  conv_all_k<<<dim3(1080, NL), 256, 0, stream>>>(Wq, Wk, Wv, Wkg, Wvg, Wqg, Wo, W1, W2, wtb);
  embed_ln_k<<<LL, 256, 0, stream>>>(emb_tok, emb_pos, ids, lnes, lneb, ginv, x, xb, xgb);

  dim3 gP2(H / 128, LL / 128, 2);
  dim3 gP4(H / 128, LL / 128, 4);
  dim3 gF(FF / 128, LL / 128);
  dim3 gQKV(H / 128, LL / 128, 6);
  for (int l = 0; l < NL; ++l) {
    u16* wt = wtb + (size_t)l * WT_ELEMS;
    gemm_qkv_k<<<gQKV, 256, 0, stream>>>(xb, xgb, wt,
        bq + l * H, bk + l * H, bv + l * H, bkg + l * H, bvg + l * H, bqg + l * H,
        qb, kb, vb, kgb, vgb, qgb);
    attn_local_k<<<dim3(NH, LL / 64), 256, 0, stream>>>(qb, kb, vb, kgb, vgb, gpos, isg, ob);
    ag_score_k<<<dim3(NH, LL / 128), 256, 0, stream>>>(qgb, kgb, sbuf);
    ag_soft_k<<<NH * 64, 256, 0, stream>>>(sbuf);
    ag_pv_k<<<dim3(NH, LL / 256), 256, 0, stream>>>(sbuf, vgb, obuf);
    ag_write_k<<<GG, 256, 0, stream>>>(obuf, gpos, ob);
    gemm_part_k<<<gP2, 256, 0, stream>>>(ob, wt + OFF_O, partb, LL, H, H);
    ln_res2_k<2><<<LL, 256, 0, stream>>>(x, partb, bo + l * H, ln1s + l * H, ln1b + l * H, ginv, xb, xgb);
    gemm_bias_k<1><<<gF, 256, 0, stream>>>(xb, wt + OFF_W1, b1 + l * FF, hb, LL, FF, H);
    gemm_part_k<<<gP4, 256, 0, stream>>>(hb, wt + OFF_W2, partb, LL, H, FF);
    ln_res2_k<4><<<LL, 256, 0, stream>>>(x, partb, b2 + l * H, ln2s + l * H, ln2b + l * H, ginv, xb, xgb);
  }
  head_k<<<NCMAX, 256, 0, stream>>>(x, posb, Wh1, bh1, Wh2, bh2, outp);
}